// Round 13
// baseline (89.855 us; speedup 1.0000x reference)
//
#include <hip/hip_runtime.h>
#include <hip/hip_bf16.h>

#define N_NODES 256
#define BATCH   1024
#define NI      8     // node indices per block
#define ROWB    528   // padded LDS row stride (bytes): imm-offset addressing,
                      // <=2-way-ish bank aliasing (~2M conflict cyc, ~3us)

typedef __attribute__((ext_vector_type(8))) short bf16x8;
typedef __attribute__((ext_vector_type(4))) float f32x4;

__device__ __forceinline__ float ftanh(float x) {
    float e = __builtin_amdgcn_exp2f(x * 2.8853900817779268f);
    float r = __builtin_amdgcn_rcpf(e + 1.0f);
    return fmaf(-2.0f, r, 1.0f);
}

__device__ __forceinline__ unsigned short f2bf(float f) {
    unsigned u = __float_as_uint(f);
    return (unsigned short)((u + 0x7fffu + ((u >> 16) & 1u)) >> 16);
}

__device__ __forceinline__ unsigned pack_bf2(float a, float b) {
    union { __hip_bfloat162 h; unsigned u; } cvt;
    cvt.h = __float22bfloat162_rn(make_float2(a, b));
    return cvt.u;
}

__device__ __forceinline__ float bf2f(short s) {
    return __uint_as_float(((unsigned)(unsigned short)s) << 16);
}

// DPP row_shr reduce; 16-lane sum lands in lane 15 (round-6 post-mortem).
template <int CTRL>
__device__ __forceinline__ float dpp_add(float s) {
    int t = __builtin_amdgcn_update_dpp(0, __float_as_int(s), CTRL, 0xf, 0xf, true);
    return s + __int_as_float(t);
}

// ---------------- P1: Z0bf = bf16(x @ W0^T) + prep ----------------
__global__ void z0_prep(const float* __restrict__ x, const float* __restrict__ W0,
                        const float* __restrict__ W1,
                        unsigned short* __restrict__ Z0bf,
                        float* __restrict__ xT, float* __restrict__ W0col,
                        unsigned short* __restrict__ W1bf) {
    __shared__ float xs[32][36];
    __shared__ float ws[32][36];
    int t = threadIdx.x;

    int gb = (blockIdx.y * 32 + blockIdx.x) * 256 + t;
    {
        int i = gb >> 8, m = gb & 255;
        W0col[gb] = W0[m * 256 + i];
        W1bf[gb]  = f2bf(W1[gb]);
    }
#pragma unroll
    for (int r = 0; r < 4; ++r) {
        int id = r * 65536 + gb;
        int i = id >> 10, b = id & 1023;
        xT[id] = x[b * 256 + i];
    }

    int b0 = blockIdx.x * 32, m0 = blockIdx.y * 32;
    int lr = t >> 3, lc = (t & 7) << 2;
    int tr = (t >> 4) << 1, tc = (t & 15) << 1;
    float acc00 = 0.f, acc01 = 0.f, acc10 = 0.f, acc11 = 0.f;
    for (int k0 = 0; k0 < 256; k0 += 32) {
        *(float4*)&xs[lr][lc] = *(const float4*)&x[(b0 + lr) * 256 + k0 + lc];
        *(float4*)&ws[lr][lc] = *(const float4*)&W0[(m0 + lr) * 256 + k0 + lc];
        __syncthreads();
#pragma unroll
        for (int k = 0; k < 32; ++k) {
            float a0 = xs[tr][k], a1 = xs[tr + 1][k];
            float w0v = ws[tc][k], w1v = ws[tc + 1][k];
            acc00 = fmaf(a0, w0v, acc00);
            acc01 = fmaf(a0, w1v, acc01);
            acc10 = fmaf(a1, w0v, acc10);
            acc11 = fmaf(a1, w1v, acc11);
        }
        __syncthreads();
    }
    Z0bf[(b0 + tr) * 256 + m0 + tc]         = f2bf(acc00);
    Z0bf[(b0 + tr) * 256 + m0 + tc + 1]     = f2bf(acc01);
    Z0bf[(b0 + tr + 1) * 256 + m0 + tc]     = f2bf(acc10);
    Z0bf[(b0 + tr + 1) * 256 + m0 + tc + 1] = f2bf(acc11);
}

// ---------------- F: operand-resident fused kernel ----------------
// Block = (64-row batch tile) x (NI node indices). Prologue: Z0 tile -> LDS
// (bf16), W1 fragments -> registers (reused across the i-loop). The per-i
// loop touches L2 only for a handful of scalars -> latency exposure gone.
__launch_bounds__(512, 2)
__global__ void fused(const unsigned short* __restrict__ Z0bf,
                      const float* __restrict__ xT,
                      const float* __restrict__ W0col,
                      const unsigned short* __restrict__ W1bf,
                      const float* __restrict__ W2, float* __restrict__ out) {
    __shared__ __align__(16) unsigned char z0s[64 * ROWB];  // 33 KiB (bf16)
    __shared__ __align__(16) unsigned char h0s[64 * ROWB];  // 33 KiB (bf16)
    __shared__ float wavepart[8 * 64];                       // 2 KiB
    const int t  = threadIdx.x;
    const int r0 = blockIdx.x * 64;   // batch tile base
    const int i0 = blockIdx.y * NI;   // node chunk base

    const int wave = t >> 6, lane = t & 63;
    const int lr = lane & 15, lh = lane >> 4;
    const int rowgrp = t >> 5, chunk = t & 31, col0 = chunk << 3;

    // ---- prologue A: stage Z0 tile -> LDS (4 rows x 8 cols per thread)
#pragma unroll
    for (int p = 0; p < 4; ++p) {
        int row = p * 16 + rowgrp;
        uint4 v = *(const uint4*)&Z0bf[(r0 + row) * 256 + col0];
        *(uint4*)(z0s + row * ROWB + chunk * 16) = v;
    }

    // ---- prologue B: this wave's W1 fragments -> registers (reused NI times)
    bf16x8 w1f[2][8];
#pragma unroll
    for (int nt = 0; nt < 2; ++nt)
#pragma unroll
        for (int ks = 0; ks < 8; ++ks)
            w1f[nt][ks] = *(const bf16x8*)&W1bf[(wave * 32 + nt * 16 + lr) * 256 + ks * 32 + lh * 8];

    __syncthreads();   // z0s ready

    for (int ii = 0; ii < NI; ++ii) {
        const int i = i0 + ii;

        // ---- phase 0: h0 = tanh(z0 - x[:,i] (x) W0[:,i]) -> LDS (bf16)
        {
            float4 w0a = *(const float4*)&W0col[i * 256 + col0];
            float4 w0b = *(const float4*)&W0col[i * 256 + col0 + 4];
            float w[8] = {w0a.x, w0a.y, w0a.z, w0a.w, w0b.x, w0b.y, w0b.z, w0b.w};
#pragma unroll
            for (int p = 0; p < 4; ++p) {
                int row = p * 16 + rowgrp;
                float xi = xT[i * 1024 + r0 + row];
                bf16x8 zv = *(const bf16x8*)(z0s + row * ROWB + chunk * 16);
                unsigned pk[4];
#pragma unroll
                for (int e = 0; e < 4; ++e) {
                    float ha = ftanh(fmaf(-xi, w[2 * e],     bf2f(zv[2 * e])));
                    float hb = ftanh(fmaf(-xi, w[2 * e + 1], bf2f(zv[2 * e + 1])));
                    pk[e] = pack_bf2(ha, hb);
                }
                *(uint4*)(h0s + row * ROWB + chunk * 16) =
                    make_uint4(pk[0], pk[1], pk[2], pk[3]);
            }
        }
        __syncthreads();   // h0 ready

        // ---- phase 1: z1 = h0 @ W1^T (W1 frags already in registers)
        f32x4 acc[4][2];
#pragma unroll
        for (int a = 0; a < 4; ++a)
#pragma unroll
            for (int b = 0; b < 2; ++b)
                acc[a][b] = (f32x4){0.f, 0.f, 0.f, 0.f};

#pragma unroll
        for (int ks = 0; ks < 8; ++ks) {
            bf16x8 afrag[4];
#pragma unroll
            for (int mt = 0; mt < 4; ++mt)
                afrag[mt] = *(const bf16x8*)(h0s + (mt * 16 + lr) * ROWB + lh * 16 + ks * 64);
#pragma unroll
            for (int mt = 0; mt < 4; ++mt) {
                acc[mt][0] = __builtin_amdgcn_mfma_f32_16x16x32_bf16(
                    afrag[mt], w1f[0][ks], acc[mt][0], 0, 0, 0);
                acc[mt][1] = __builtin_amdgcn_mfma_f32_16x16x32_bf16(
                    afrag[mt], w1f[1][ks], acc[mt][1], 0, 0, 0);
            }
        }

        // ---- phase 2: tanh + dot with W2 row i; DPP reduce (sum at lane 15)
        const float w2v0 = W2[i * 256 + wave * 32 + lr];
        const float w2v1 = W2[i * 256 + wave * 32 + 16 + lr];
#pragma unroll
        for (int mt = 0; mt < 4; ++mt) {
#pragma unroll
            for (int r = 0; r < 4; ++r) {
                float s = fmaf(ftanh(acc[mt][0][r]), w2v0,
                               ftanh(acc[mt][1][r]) * w2v1);
                s = dpp_add<0x118>(s);
                s = dpp_add<0x114>(s);
                s = dpp_add<0x112>(s);
                s = dpp_add<0x111>(s);
                if (lr == 15)
                    wavepart[wave * 64 + mt * 16 + lh * 4 + r] = s;
            }
        }
        __syncthreads();   // wavepart ready; h0 reads done (safe to overwrite)

        // ---- phase 3: final reduce + tanh + store (runs ahead of next phase0;
        //      wavepart is not rewritten until after the next barrier)
        if (t < 64) {
            float s = 0.f;
#pragma unroll
            for (int w = 0; w < 8; ++w) s += wavepart[w * 64 + t];
            out[(r0 + t) * 256 + i] = ftanh(s);
        }
    }
}

extern "C" void kernel_launch(void* const* d_in, const int* in_sizes, int n_in,
                              void* d_out, int out_size, void* d_ws, size_t ws_size,
                              hipStream_t stream) {
    const float* x  = (const float*)d_in[0];
    const float* W0 = (const float*)d_in[1];
    const float* W1 = (const float*)d_in[2];
    const float* W2 = (const float*)d_in[3];
    float* out = (float*)d_out;

    char* ws = (char*)d_ws;
    unsigned short* Z0bf = (unsigned short*)ws;                      // 512 KB
    float* xT            = (float*)(ws + (512 << 10));               // 1 MB
    float* W0col         = (float*)(ws + (512 << 10) + (1 << 20));   // 256 KB
    unsigned short* W1bf = (unsigned short*)(ws + (512 << 10) + (1 << 20) + (256 << 10)); // 128 KB

    z0_prep<<<dim3(32, 8), 256, 0, stream>>>(x, W0, W1, Z0bf, xT, W0col, W1bf);
    fused<<<dim3(16, 256 / NI), 512, 0, stream>>>(Z0bf, xT, W0col, W1bf, W2, out);
}